// Round 18
// baseline (40.226 us; speedup 1.0000x reference)
//
#include <hip/hip_runtime.h>

// E = 8*128*128 edges; MLP 16->128->256->128->(32x32 folded to 32)
// Round 18: R10's 2-tile register-resident chain (proven, ~124 live VGPR)
// + W2s-only LDS (64 KB -> 2 blocks/CU -> ONE dispatch round of 512 blocks
// at 4 waves/SIMD) + (512,2) (VGPR cap 128; R12's (512,4) forced 64+spill).
// W1/W3/W4 frags stream from L2 (W3 = 256 MB aggregate ~ 8us, overlapped).

typedef _Float16 f16;
typedef _Float16 f16x8 __attribute__((ext_vector_type(8)));
typedef __fp16 fp16x2 __attribute__((ext_vector_type(2)));
typedef float f32x4 __attribute__((ext_vector_type(4)));

#define OFF_W1S 0        // [8 ct][64 lane][8]  (K=16 padded: k16 = b1) natural k
#define OFF_W2S 4096     // [16 ct][4 kt][64][8]  F-permuted k
#define OFF_W3S 36864    // [8 ct][8 kt][64][8]   F-permuted k
#define OFF_W4S 69632    // [2 ct][4 kt][64][8]   F-permuted k, folded over i
#define WS_HALFS 73728

union U16x8 { struct { uint2 lo, hi; } p; f16x8 v; };
union U32x2 { fp16x2 h2[2]; uint2 u; };

// ---------------------------------------------------------------------------
// Pre-kernel. A-frag element j of lane l (u=(l>>4)&3) for (ct, kt) holds
// W[k_feat][ct*16 + (l&15)] with k_feat = kt*32 + (j>>2)*16 + u*4 + (j&3)
// (the F-labeling matching register-resident activations). W1 keeps natural
// k = u*8 + j (input from global in natural order), row 16 = b1.
// ---------------------------------------------------------------------------
__global__ void prep_kernel(const float* __restrict__ W1, const float* __restrict__ b1,
                            const float* __restrict__ W2, const float* __restrict__ W3,
                            const float* __restrict__ W4, const float* __restrict__ b4,
                            f16* __restrict__ wsh, float* __restrict__ b4r) {
  int t = blockIdx.x * 256 + threadIdx.x;
  if (t < 4096) {                       // W1s: natural k (16 + bias row + zeros)
    int j = t & 7, lq = (t >> 3) & 63, ct = t >> 9;
    int k = ((lq >> 4) & 3) * 8 + j, c = ct * 16 + (lq & 15);
    wsh[OFF_W1S + t] = (k < 16) ? (f16)W1[k * 128 + c]
                                : (k == 16 ? (f16)b1[c] : (f16)0.f);
  } else if (t < 36864) {               // W2s: F-permuted
    int s = t - 4096;
    int j = s & 7, lq = (s >> 3) & 63, kt = (s >> 9) & 3, ct = s >> 11;
    int u = (lq >> 4) & 3;
    int k = kt * 32 + (j >> 2) * 16 + u * 4 + (j & 3), c = ct * 16 + (lq & 15);
    wsh[t] = (f16)W2[k * 256 + c];
  } else if (t < 69632) {               // W3s: F-permuted
    int s = t - 36864;
    int j = s & 7, lq = (s >> 3) & 63, kt = (s >> 9) & 7, ct = s >> 12;
    int u = (lq >> 4) & 3;
    int k = kt * 32 + (j >> 2) * 16 + u * 4 + (j & 3), c = ct * 16 + (lq & 15);
    wsh[t] = (f16)W3[k * 128 + c];
  } else if (t < 73728) {               // W4s: F-permuted, folded over inner i
    int s = t - 69632;
    int j = s & 7, lq = (s >> 3) & 63, kt = (s >> 9) & 3, ct = s >> 11;
    int u = (lq >> 4) & 3;
    int k = kt * 32 + (j >> 2) * 16 + u * 4 + (j & 3), o = ct * 16 + (lq & 15);
    float a = 0.f;
#pragma unroll
    for (int i = 0; i < 32; ++i) a += W4[k * 1024 + o * 32 + i];
    wsh[t] = (f16)a;
  }
  if (t < 32) {
    float a = 0.f;
#pragma unroll
    for (int i = 0; i < 32; ++i) a += b4[t * 32 + i];
    b4r[t] = a;
  }
}

__device__ __forceinline__ uint2 relu_pack(f32x4 a) {
  U32x2 o;
  o.h2[0] = __builtin_amdgcn_cvt_pkrtz(fmaxf(a[0], 0.f), fmaxf(a[1], 0.f));
  o.h2[1] = __builtin_amdgcn_cvt_pkrtz(fmaxf(a[2], 0.f), fmaxf(a[3], 0.f));
  return o.u;
}
__device__ __forceinline__ uint2 bias_relu_pack(f32x4 a, float4 b) {
  U32x2 o;
  o.h2[0] = __builtin_amdgcn_cvt_pkrtz(fmaxf(a[0] + b.x, 0.f), fmaxf(a[1] + b.y, 0.f));
  o.h2[1] = __builtin_amdgcn_cvt_pkrtz(fmaxf(a[2] + b.z, 0.f), fmaxf(a[3] + b.w, 0.f));
  return o.u;
}

// ---------------------------------------------------------------------------
// Fused MLP: 512 threads (8 waves), 2 blocks/CU (64 KB LDS), grid 512 in one
// dispatch round = 4 waves/SIMD. Each wave owns 32 edges (2 tiles; frags
// loaded once, used twice). Activations in VGPRs end-to-end; one barrier.
// ---------------------------------------------------------------------------
__global__ __launch_bounds__(512, 2) void mlp_mfma_kernel(
    const float* __restrict__ e_vw, const float* __restrict__ h_w,
    const float* __restrict__ b2, const float* __restrict__ b3,
    const f16* __restrict__ wsh, const float* __restrict__ b4r,
    float* __restrict__ out) {
  __shared__ f16 WT[32768];   // 64 KB: W2s' only

  const int tid = threadIdx.x;
  const int l = tid & 63, w = tid >> 6;
  const int e0 = l & 15, u = l >> 4;
  const size_t base = (size_t)blockIdx.x * 256 + (size_t)w * 32;

  const f16x8* wp1 = (const f16x8*)(wsh + OFF_W1S);
  const f16x8* wp3 = (const f16x8*)(wsh + OFF_W3S);
  const f16x8* wp4 = (const f16x8*)(wsh + OFF_W4S);

  // ---- stage inputs + W1 frags (global; overlaps preload) ----
  U16x8 xin[2];
#pragma unroll
  for (int ti = 0; ti < 2; ++ti) {
    if (u < 2) {
      const float* pe = e_vw + (base + ti * 16 + e0) * 16 + u * 8;
      float4 v0 = *reinterpret_cast<const float4*>(pe);
      float4 v1 = *reinterpret_cast<const float4*>(pe + 4);
      U32x2 c0, c1;
      c0.h2[0] = __builtin_amdgcn_cvt_pkrtz(v0.x, v0.y);
      c0.h2[1] = __builtin_amdgcn_cvt_pkrtz(v0.z, v0.w);
      c1.h2[0] = __builtin_amdgcn_cvt_pkrtz(v1.x, v1.y);
      c1.h2[1] = __builtin_amdgcn_cvt_pkrtz(v1.z, v1.w);
      xin[ti].p.lo = c0.u; xin[ti].p.hi = c1.u;
    } else {
      xin[ti].p.lo.x = (u == 2) ? 0x00003C00u : 0u;  // k=16 -> 1.0 (bias slot)
      xin[ti].p.lo.y = 0u; xin[ti].p.hi.x = 0u; xin[ti].p.hi.y = 0u;
    }
  }

  // ---- preload W2s' into LDS (65536 B, 8 float4 per thread) ----
  {
    const float4* src = (const float4*)(wsh + OFF_W2S);
    float4* dst = (float4*)WT;
#pragma unroll
    for (int i = 0; i < 8; ++i) dst[tid + i * 512] = src[tid + i * 512];
  }
  __syncthreads();

  // ---- L1: 16 -> 128 (bias folded in K-pad; W1 frags from L2) ----
  U16x8 x1[2][4];
  const f32x4 z4 = {0.f, 0.f, 0.f, 0.f};
#pragma unroll
  for (int ct = 0; ct < 8; ++ct) {
    f16x8 wf = wp1[ct * 64 + l];
    f32x4 a0 = __builtin_amdgcn_mfma_f32_16x16x32_f16(wf, xin[0].v, z4, 0, 0, 0);
    f32x4 a1 = __builtin_amdgcn_mfma_f32_16x16x32_f16(wf, xin[1].v, z4, 0, 0, 0);
    uint2 d0 = relu_pack(a0), d1 = relu_pack(a1);
    if (ct & 1) { x1[0][ct >> 1].p.hi = d0; x1[1][ct >> 1].p.hi = d1; }
    else        { x1[0][ct >> 1].p.lo = d0; x1[1][ct >> 1].p.lo = d1; }
  }

  // ---- L2: 128 -> 256 (weights from LDS; B-frag = x1[kt] directly) ----
  U16x8 x2[2][8];
#pragma unroll
  for (int ct = 0; ct < 16; ++ct) {
    f32x4 a0 = z4, a1 = z4;
#pragma unroll
    for (int kt = 0; kt < 4; ++kt) {
      f16x8 wf = *(const f16x8*)(WT + ((ct * 4 + kt) * 64 + l) * 8);
      a0 = __builtin_amdgcn_mfma_f32_16x16x32_f16(wf, x1[0][kt].v, a0, 0, 0, 0);
      a1 = __builtin_amdgcn_mfma_f32_16x16x32_f16(wf, x1[1][kt].v, a1, 0, 0, 0);
    }
    float4 bb = *reinterpret_cast<const float4*>(b2 + ct * 16 + u * 4);
    uint2 d0 = bias_relu_pack(a0, bb), d1 = bias_relu_pack(a1, bb);
    if (ct & 1) { x2[0][ct >> 1].p.hi = d0; x2[1][ct >> 1].p.hi = d1; }
    else        { x2[0][ct >> 1].p.lo = d0; x2[1][ct >> 1].p.lo = d1; }
  }

  // ---- L3: 256 -> 128 (weights stream from L2; 64 KB shared by all waves) -
  U16x8 x3[2][4];
#pragma unroll
  for (int ct = 0; ct < 8; ++ct) {
    f32x4 a0 = z4, a1 = z4;
#pragma unroll
    for (int kt = 0; kt < 8; ++kt) {
      f16x8 wf = wp3[(ct * 8 + kt) * 64 + l];
      a0 = __builtin_amdgcn_mfma_f32_16x16x32_f16(wf, x2[0][kt].v, a0, 0, 0, 0);
      a1 = __builtin_amdgcn_mfma_f32_16x16x32_f16(wf, x2[1][kt].v, a1, 0, 0, 0);
    }
    float4 bb = *reinterpret_cast<const float4*>(b3 + ct * 16 + u * 4);
    uint2 d0 = bias_relu_pack(a0, bb), d1 = bias_relu_pack(a1, bb);
    if (ct & 1) { x3[0][ct >> 1].p.hi = d0; x3[1][ct >> 1].p.hi = d1; }
    else        { x3[0][ct >> 1].p.lo = d0; x3[1][ct >> 1].p.lo = d1; }
  }

  // ---- L4: 128 -> 32 (folded), scale by s_e, coalesced float4 store ----
#pragma unroll
  for (int ti = 0; ti < 2; ++ti) {
    size_t e = base + ti * 16 + e0;
    float s = h_w[(e >> 7) * 32 + ((e & 127) >> 2)];
#pragma unroll
    for (int ct = 0; ct < 2; ++ct) {
      f32x4 acc = z4;
#pragma unroll
      for (int kt = 0; kt < 4; ++kt)
        acc = __builtin_amdgcn_mfma_f32_16x16x32_f16(wp4[(ct * 4 + kt) * 64 + l],
                                                     x3[ti][kt].v, acc, 0, 0, 0);
      float4 bb = *reinterpret_cast<const float4*>(b4r + ct * 16 + u * 4);
      float4 st;
      st.x = s * (acc[0] + bb.x); st.y = s * (acc[1] + bb.y);
      st.z = s * (acc[2] + bb.z); st.w = s * (acc[3] + bb.w);
      *reinterpret_cast<float4*>(out + e * 32 + ct * 16 + u * 4) = st;
    }
  }
}

// ---------------------------------------------------------------------------
extern "C" void kernel_launch(void* const* d_in, const int* in_sizes, int n_in,
                              void* d_out, int out_size, void* d_ws, size_t ws_size,
                              hipStream_t stream) {
  // inputs: h_v, h_w, e_vw, W1, b1, W2, b2, W3, b3, W4, b4
  const float* h_w  = (const float*)d_in[1];
  const float* e_vw = (const float*)d_in[2];
  const float* W1   = (const float*)d_in[3];
  const float* b1   = (const float*)d_in[4];
  const float* W2   = (const float*)d_in[5];
  const float* b2   = (const float*)d_in[6];
  const float* W3   = (const float*)d_in[7];
  const float* b3   = (const float*)d_in[8];
  const float* W4   = (const float*)d_in[9];
  const float* b4   = (const float*)d_in[10];
  float* out = (float*)d_out;

  f16*   wsh = (f16*)d_ws;
  float* b4r = (float*)((char*)d_ws + (size_t)WS_HALFS * 2);

  const int E = in_sizes[2] / 16;       // 131072
  const int blocks = E / 256;           // 512 (8 waves x 32 edges each)

  hipLaunchKernelGGL(prep_kernel, dim3(288), dim3(256), 0, stream,
                     W1, b1, W2, W3, W4, b4, wsh, b4r);
  hipLaunchKernelGGL(mlp_mfma_kernel, dim3(blocks), dim3(512), 0, stream,
                     e_vw, h_w, b2, b3, wsh, b4r, out);
}

// Round 20
// 35.564 us; speedup vs baseline: 1.1311x; 1.1311x over previous
//
#include <hip/hip_runtime.h>

// E = 8*128*128 edges; MLP 16->128->256->128->(32x32 folded to 32)
// Round 20 = round 19 resubmit (container died pre-delivery).
// R10 chain with FOUR tiles (64 edges) per wave. Insight: R10 is LDS-bound
// to 1 block/CU (128KB weights) = 2 waves/SIMD, where the VGPR budget is
// 512/2 = 256 -- R10 used only ~124. NT=4 spends the idle half: 2x better
// frag amortization, grid 256 = ONE dispatch round, and 4 independent MFMA
// chains per kt-step hide dependent-MFMA latency in-wave. Peak live ~225
// VGPR <= 256 cap of (512,2). Weights stay LDS-resident (R13/R18: L2 loses).

typedef _Float16 f16;
typedef _Float16 f16x8 __attribute__((ext_vector_type(8)));
typedef __fp16 fp16x2 __attribute__((ext_vector_type(2)));
typedef float f32x4 __attribute__((ext_vector_type(4)));

#define OFF_W1S 0        // [8 ct][64 lane][8]  (K=16 padded: k16 = b1) natural k
#define OFF_W2S 4096     // [16 ct][4 kt][64][8]  F-permuted k
#define OFF_W3S 36864    // [8 ct][8 kt][64][8]   F-permuted k
#define OFF_W4S 69632    // [2 ct][4 kt][64][8]   F-permuted k, folded over i
#define WS_HALFS 73728
#define NT 4             // tiles (of 16 edges) per wave

union U16x8 { struct { uint2 lo, hi; } p; f16x8 v; };
union U32x2 { fp16x2 h2[2]; uint2 u; };

// ---------------------------------------------------------------------------
// Pre-kernel. A-frag element j of lane l (u=(l>>4)&3) for (ct, kt) holds
// W[k_feat][ct*16 + (l&15)] with k_feat = kt*32 + (j>>2)*16 + u*4 + (j&3)
// (the F-labeling matching register-resident activations). W1 keeps natural
// k = u*8 + j (input from global in natural order), row 16 = b1.
// ---------------------------------------------------------------------------
__global__ void prep_kernel(const float* __restrict__ W1, const float* __restrict__ b1,
                            const float* __restrict__ W2, const float* __restrict__ W3,
                            const float* __restrict__ W4, const float* __restrict__ b4,
                            f16* __restrict__ wsh, float* __restrict__ b4r) {
  int t = blockIdx.x * 256 + threadIdx.x;
  if (t < 4096) {                       // W1s: natural k (16 + bias row + zeros)
    int j = t & 7, lq = (t >> 3) & 63, ct = t >> 9;
    int k = ((lq >> 4) & 3) * 8 + j, c = ct * 16 + (lq & 15);
    wsh[OFF_W1S + t] = (k < 16) ? (f16)W1[k * 128 + c]
                                : (k == 16 ? (f16)b1[c] : (f16)0.f);
  } else if (t < 36864) {               // W2s: F-permuted
    int s = t - 4096;
    int j = s & 7, lq = (s >> 3) & 63, kt = (s >> 9) & 3, ct = s >> 11;
    int u = (lq >> 4) & 3;
    int k = kt * 32 + (j >> 2) * 16 + u * 4 + (j & 3), c = ct * 16 + (lq & 15);
    wsh[t] = (f16)W2[k * 256 + c];
  } else if (t < 69632) {               // W3s: F-permuted
    int s = t - 36864;
    int j = s & 7, lq = (s >> 3) & 63, kt = (s >> 9) & 7, ct = s >> 12;
    int u = (lq >> 4) & 3;
    int k = kt * 32 + (j >> 2) * 16 + u * 4 + (j & 3), c = ct * 16 + (lq & 15);
    wsh[t] = (f16)W3[k * 128 + c];
  } else if (t < 73728) {               // W4s: F-permuted, folded over inner i
    int s = t - 69632;
    int j = s & 7, lq = (s >> 3) & 63, kt = (s >> 9) & 3, ct = s >> 11;
    int u = (lq >> 4) & 3;
    int k = kt * 32 + (j >> 2) * 16 + u * 4 + (j & 3), o = ct * 16 + (lq & 15);
    float a = 0.f;
#pragma unroll
    for (int i = 0; i < 32; ++i) a += W4[k * 1024 + o * 32 + i];
    wsh[t] = (f16)a;
  }
  if (t < 32) {
    float a = 0.f;
#pragma unroll
    for (int i = 0; i < 32; ++i) a += b4[t * 32 + i];
    b4r[t] = a;
  }
}

__device__ __forceinline__ uint2 relu_pack(f32x4 a) {
  U32x2 o;
  o.h2[0] = __builtin_amdgcn_cvt_pkrtz(fmaxf(a[0], 0.f), fmaxf(a[1], 0.f));
  o.h2[1] = __builtin_amdgcn_cvt_pkrtz(fmaxf(a[2], 0.f), fmaxf(a[3], 0.f));
  return o.u;
}
__device__ __forceinline__ uint2 bias_relu_pack(f32x4 a, float4 b) {
  U32x2 o;
  o.h2[0] = __builtin_amdgcn_cvt_pkrtz(fmaxf(a[0] + b.x, 0.f), fmaxf(a[1] + b.y, 0.f));
  o.h2[1] = __builtin_amdgcn_cvt_pkrtz(fmaxf(a[2] + b.z, 0.f), fmaxf(a[3] + b.w, 0.f));
  return o.u;
}

// ---------------------------------------------------------------------------
// Fused MLP: 512 threads (8 waves), 1 block/CU (128 KB LDS), grid 256 =
// single dispatch round. Each wave owns 64 edges (4 16-edge tiles; weight
// frags loaded once, used 4x; 4 independent MFMA chains per kt).
// Activations in VGPRs end-to-end; one barrier (weight preload).
// ---------------------------------------------------------------------------
__global__ __launch_bounds__(512, 2) void mlp_mfma_kernel(
    const float* __restrict__ e_vw, const float* __restrict__ h_w,
    const float* __restrict__ b2, const float* __restrict__ b3,
    const f16* __restrict__ wsh, const float* __restrict__ b4r,
    float* __restrict__ out) {
  __shared__ f16 WT[65536];   // 128 KB: [0,32768) W2s', [32768,65536) W3s'

  const int tid = threadIdx.x;
  const int l = tid & 63, w = tid >> 6;
  const int e0 = l & 15, u = l >> 4;
  const size_t base = (size_t)blockIdx.x * 512 + (size_t)w * 64;

  const f16x8* wp1 = (const f16x8*)(wsh + OFF_W1S);
  const f16x8* wp4 = (const f16x8*)(wsh + OFF_W4S);

  // ---- stage inputs (global; overlaps preload) ----
  U16x8 xin[NT];
#pragma unroll
  for (int ti = 0; ti < NT; ++ti) {
    if (u < 2) {
      const float* pe = e_vw + (base + ti * 16 + e0) * 16 + u * 8;
      float4 v0 = *reinterpret_cast<const float4*>(pe);
      float4 v1 = *reinterpret_cast<const float4*>(pe + 4);
      U32x2 c0, c1;
      c0.h2[0] = __builtin_amdgcn_cvt_pkrtz(v0.x, v0.y);
      c0.h2[1] = __builtin_amdgcn_cvt_pkrtz(v0.z, v0.w);
      c1.h2[0] = __builtin_amdgcn_cvt_pkrtz(v1.x, v1.y);
      c1.h2[1] = __builtin_amdgcn_cvt_pkrtz(v1.z, v1.w);
      xin[ti].p.lo = c0.u; xin[ti].p.hi = c1.u;
    } else {
      xin[ti].p.lo.x = (u == 2) ? 0x00003C00u : 0u;  // k=16 -> 1.0 (bias slot)
      xin[ti].p.lo.y = 0u; xin[ti].p.hi.x = 0u; xin[ti].p.hi.y = 0u;
    }
  }

  // ---- preload W2s'/W3s' into LDS (131072 B, 16 float4 per thread) ----
  {
    const float4* src = (const float4*)(wsh + OFF_W2S);
    float4* dst = (float4*)WT;
#pragma unroll
    for (int i = 0; i < 16; ++i) dst[tid + i * 512] = src[tid + i * 512];
  }
  __syncthreads();

  const f32x4 z4 = {0.f, 0.f, 0.f, 0.f};

  // ---- L1: 16 -> 128 (bias folded in K-pad; W1 frags from L2) ----
  U16x8 x1[NT][4];
#pragma unroll
  for (int ct = 0; ct < 8; ++ct) {
    f16x8 wf = wp1[ct * 64 + l];
    f32x4 a[NT];
#pragma unroll
    for (int ti = 0; ti < NT; ++ti)
      a[ti] = __builtin_amdgcn_mfma_f32_16x16x32_f16(wf, xin[ti].v, z4, 0, 0, 0);
#pragma unroll
    for (int ti = 0; ti < NT; ++ti) {
      uint2 d = relu_pack(a[ti]);
      if (ct & 1) x1[ti][ct >> 1].p.hi = d; else x1[ti][ct >> 1].p.lo = d;
    }
  }

  // ---- L2: 128 -> 256 (weights from LDS; B-frag = x1[kt] directly) ----
  U16x8 x2[NT][8];
#pragma unroll
  for (int ct = 0; ct < 16; ++ct) {
    f32x4 a[NT];
#pragma unroll
    for (int ti = 0; ti < NT; ++ti) a[ti] = z4;
#pragma unroll
    for (int kt = 0; kt < 4; ++kt) {
      f16x8 wf = *(const f16x8*)(WT + ((ct * 4 + kt) * 64 + l) * 8);
#pragma unroll
      for (int ti = 0; ti < NT; ++ti)
        a[ti] = __builtin_amdgcn_mfma_f32_16x16x32_f16(wf, x1[ti][kt].v, a[ti], 0, 0, 0);
    }
    float4 bb = *reinterpret_cast<const float4*>(b2 + ct * 16 + u * 4);
#pragma unroll
    for (int ti = 0; ti < NT; ++ti) {
      uint2 d = bias_relu_pack(a[ti], bb);
      if (ct & 1) x2[ti][ct >> 1].p.hi = d; else x2[ti][ct >> 1].p.lo = d;
    }
  }

  // ---- L3: 256 -> 128 (weights from LDS) ----
  U16x8 x3[NT][4];
#pragma unroll
  for (int ct = 0; ct < 8; ++ct) {
    f32x4 a[NT];
#pragma unroll
    for (int ti = 0; ti < NT; ++ti) a[ti] = z4;
#pragma unroll
    for (int kt = 0; kt < 8; ++kt) {
      f16x8 wf = *(const f16x8*)(WT + 32768 + ((ct * 8 + kt) * 64 + l) * 8);
#pragma unroll
      for (int ti = 0; ti < NT; ++ti)
        a[ti] = __builtin_amdgcn_mfma_f32_16x16x32_f16(wf, x2[ti][kt].v, a[ti], 0, 0, 0);
    }
    float4 bb = *reinterpret_cast<const float4*>(b3 + ct * 16 + u * 4);
#pragma unroll
    for (int ti = 0; ti < NT; ++ti) {
      uint2 d = bias_relu_pack(a[ti], bb);
      if (ct & 1) x3[ti][ct >> 1].p.hi = d; else x3[ti][ct >> 1].p.lo = d;
    }
  }

  // ---- L4: 128 -> 32 (folded), scale by s_e, coalesced float4 store ----
#pragma unroll
  for (int ct = 0; ct < 2; ++ct) {
    f16x8 bfr4[4];
#pragma unroll
    for (int kt = 0; kt < 4; ++kt) bfr4[kt] = wp4[(ct * 4 + kt) * 64 + l];
    float4 bb = *reinterpret_cast<const float4*>(b4r + ct * 16 + u * 4);
#pragma unroll
    for (int ti = 0; ti < NT; ++ti) {
      f32x4 acc = z4;
#pragma unroll
      for (int kt = 0; kt < 4; ++kt)
        acc = __builtin_amdgcn_mfma_f32_16x16x32_f16(bfr4[kt], x3[ti][kt].v, acc, 0, 0, 0);
      size_t e = base + ti * 16 + e0;
      float s = h_w[(e >> 7) * 32 + ((e & 127) >> 2)];
      float4 st;
      st.x = s * (acc[0] + bb.x); st.y = s * (acc[1] + bb.y);
      st.z = s * (acc[2] + bb.z); st.w = s * (acc[3] + bb.w);
      *reinterpret_cast<float4*>(out + e * 32 + ct * 16 + u * 4) = st;
    }
  }
}

// ---------------------------------------------------------------------------
extern "C" void kernel_launch(void* const* d_in, const int* in_sizes, int n_in,
                              void* d_out, int out_size, void* d_ws, size_t ws_size,
                              hipStream_t stream) {
  // inputs: h_v, h_w, e_vw, W1, b1, W2, b2, W3, b3, W4, b4
  const float* h_w  = (const float*)d_in[1];
  const float* e_vw = (const float*)d_in[2];
  const float* W1   = (const float*)d_in[3];
  const float* b1   = (const float*)d_in[4];
  const float* W2   = (const float*)d_in[5];
  const float* b2   = (const float*)d_in[6];
  const float* W3   = (const float*)d_in[7];
  const float* b3   = (const float*)d_in[8];
  const float* W4   = (const float*)d_in[9];
  const float* b4   = (const float*)d_in[10];
  float* out = (float*)d_out;

  f16*   wsh = (f16*)d_ws;
  float* b4r = (float*)((char*)d_ws + (size_t)WS_HALFS * 2);

  const int E = in_sizes[2] / 16;       // 131072
  const int blocks = E / 512;           // 256 = 1 block/CU, single round

  hipLaunchKernelGGL(prep_kernel, dim3(288), dim3(256), 0, stream,
                     W1, b1, W2, W3, W4, b4, wsh, b4r);
  hipLaunchKernelGGL(mlp_mfma_kernel, dim3(blocks), dim3(512), 0, stream,
                     e_vw, h_w, b2, b3, wsh, b4r, out);
}